// Round 16
// baseline (667.867 us; speedup 1.0000x reference)
//
#include <hip/hip_runtime.h>
#include <hip/hip_bf16.h>

#define B_   2
#define T_   2048
#define D_   2048
#define H_   16
#define DH_  128
#define DFF_ 8192

typedef __attribute__((ext_vector_type(8))) short bf16x8;
typedef __attribute__((ext_vector_type(4))) float f32x4;

__device__ __forceinline__ short f2bf(float f) {
    __hip_bfloat16 h = __float2bfloat16(f);
    return *reinterpret_cast<short*>(&h);
}

__device__ __forceinline__ void gload_lds16(const void* g, void* l) {
    __builtin_amdgcn_global_load_lds(
        (const __attribute__((address_space(1))) void*)g,
        (__attribute__((address_space(3))) void*)l,
        16, 0, 0);
}

// gelu_tanh(x) = 0.5x(1+tanh(z)) == x/(1+exp(-2z)); exact identity.
__device__ __forceinline__ float gelu_fast(float x) {
    float z = 0.7978845608028654f * (x + 0.044715f * x * x * x);
    return x / (1.f + __expf(-2.f * z));
}

#define MFMA32(a, b, c) __builtin_amdgcn_mfma_f32_16x16x32_bf16((a), (b), (c), 0, 0, 0)

// ---------------------------------------------------------------------------
// Transpose + f32->bf16 convert (frozen; used for w1, w2)
// ---------------------------------------------------------------------------
__global__ __launch_bounds__(256) void transpose_cvt(const float* __restrict__ in,
                                                     __hip_bfloat16* __restrict__ out,
                                                     int K, int N, int out_ld, int out_row0)
{
    __shared__ float t[32][65];
    const int n0 = blockIdx.x * 64, k0 = blockIdx.y * 32;
    const int tid = threadIdx.x;
    {
        int kr = tid >> 4;
        int nc = (tid & 15) * 4;
        const float* src = in + (size_t)(k0 + kr) * N + n0 + nc;
        float4 a = *reinterpret_cast<const float4*>(src);
        float4 b = *reinterpret_cast<const float4*>(src + (size_t)16 * N);
        t[kr][nc] = a.x; t[kr][nc + 1] = a.y; t[kr][nc + 2] = a.z; t[kr][nc + 3] = a.w;
        t[kr + 16][nc] = b.x; t[kr + 16][nc + 1] = b.y; t[kr + 16][nc + 2] = b.z; t[kr + 16][nc + 3] = b.w;
    }
    __syncthreads();
    {
        int n  = tid >> 2;
        int kc = (tid & 3) * 8;
        __hip_bfloat16 ob[8];
#pragma unroll
        for (int j = 0; j < 8; ++j) ob[j] = __float2bfloat16(t[kc + j][n]);
        *reinterpret_cast<uint4*>(out + (size_t)(out_row0 + n0 + n) * out_ld + k0 + kc) =
            *reinterpret_cast<uint4*>(ob);
    }
}

// ---------------------------------------------------------------------------
// Merged 4x square (2048^2) weight transpose: z selects wq/wk/wv/wo.
// ---------------------------------------------------------------------------
__global__ __launch_bounds__(256) void transpose_cvt4(
    const float* __restrict__ wq, const float* __restrict__ wk,
    const float* __restrict__ wv, const float* __restrict__ wo,
    __hip_bfloat16* __restrict__ oqkv, __hip_bfloat16* __restrict__ owo)
{
    const int z = blockIdx.z;
    const float* in = (z == 0) ? wq : (z == 1) ? wk : (z == 2) ? wv : wo;
    __hip_bfloat16* out = (z < 3) ? (oqkv + (size_t)z * 2048 * 2048) : owo;

    __shared__ float t[32][65];
    const int n0 = blockIdx.x * 64, k0 = blockIdx.y * 32;
    const int tid = threadIdx.x;
    {
        int kr = tid >> 4;
        int nc = (tid & 15) * 4;
        const float* src = in + (size_t)(k0 + kr) * 2048 + n0 + nc;
        float4 a = *reinterpret_cast<const float4*>(src);
        float4 b = *reinterpret_cast<const float4*>(src + (size_t)16 * 2048);
        t[kr][nc] = a.x; t[kr][nc + 1] = a.y; t[kr][nc + 2] = a.z; t[kr][nc + 3] = a.w;
        t[kr + 16][nc] = b.x; t[kr + 16][nc + 1] = b.y; t[kr + 16][nc + 2] = b.z; t[kr + 16][nc + 3] = b.w;
    }
    __syncthreads();
    {
        int n  = tid >> 2;
        int kc = (tid & 3) * 8;
        __hip_bfloat16 ob[8];
#pragma unroll
        for (int j = 0; j < 8; ++j) ob[j] = __float2bfloat16(t[kc + j][n]);
        *reinterpret_cast<uint4*>(out + (size_t)(n0 + n) * 2048 + k0 + kc) =
            *reinterpret_cast<uint4*>(ob);
    }
}

// ---------------------------------------------------------------------------
// LayerNorm, f32 input (frozen; LN1)
// ---------------------------------------------------------------------------
__global__ __launch_bounds__(256) void ln_kernel(const float* __restrict__ x,
                                                 const float* __restrict__ sc,
                                                 const float* __restrict__ of,
                                                 __hip_bfloat16* __restrict__ out)
{
    int row = blockIdx.x, tid = threadIdx.x;
    const float* xr = x + (size_t)row * D_;
    float4 v0 = reinterpret_cast<const float4*>(xr)[tid * 2];
    float4 v1 = reinterpret_cast<const float4*>(xr)[tid * 2 + 1];
    float vv[8] = {v0.x, v0.y, v0.z, v0.w, v1.x, v1.y, v1.z, v1.w};
    float s = 0.f, ss = 0.f;
#pragma unroll
    for (int j = 0; j < 8; ++j) { s += vv[j]; ss += vv[j] * vv[j]; }
    for (int o = 32; o; o >>= 1) { s += __shfl_down(s, o); ss += __shfl_down(ss, o); }
    __shared__ float red[8];
    int wid = tid >> 6, lane = tid & 63;
    if (!lane) { red[wid] = s; red[4 + wid] = ss; }
    __syncthreads();
    s  = red[0] + red[1] + red[2] + red[3];
    ss = red[4] + red[5] + red[6] + red[7];
    float mean = s * (1.f / D_);
    float var  = ss * (1.f / D_) - mean * mean;
    float rstd = rsqrtf(var + 1e-5f);
    int c0 = tid * 8;
    __hip_bfloat16 ob[8];
#pragma unroll
    for (int j = 0; j < 8; ++j)
        ob[j] = __float2bfloat16((vv[j] - mean) * rstd * sc[c0 + j] + of[c0 + j]);
    *reinterpret_cast<uint4*>(out + (size_t)row * D_ + c0) = *reinterpret_cast<uint4*>(ob);
}

// ---------------------------------------------------------------------------
// LayerNorm, bf16 input (LN2; frozen)
// ---------------------------------------------------------------------------
__global__ __launch_bounds__(256) void ln_bf16_kernel(const __hip_bfloat16* __restrict__ x,
                                                      const float* __restrict__ sc,
                                                      const float* __restrict__ of,
                                                      __hip_bfloat16* __restrict__ out)
{
    int row = blockIdx.x, tid = threadIdx.x;
    uint4 u = *reinterpret_cast<const uint4*>(x + (size_t)row * D_ + tid * 8);
    const unsigned short* us = reinterpret_cast<const unsigned short*>(&u);
    float vv[8];
#pragma unroll
    for (int j = 0; j < 8; ++j)
        vv[j] = __uint_as_float((unsigned)us[j] << 16);
    float s = 0.f, ss = 0.f;
#pragma unroll
    for (int j = 0; j < 8; ++j) { s += vv[j]; ss += vv[j] * vv[j]; }
    for (int o = 32; o; o >>= 1) { s += __shfl_down(s, o); ss += __shfl_down(ss, o); }
    __shared__ float red[8];
    int wid = tid >> 6, lane = tid & 63;
    if (!lane) { red[wid] = s; red[4 + wid] = ss; }
    __syncthreads();
    s  = red[0] + red[1] + red[2] + red[3];
    ss = red[4] + red[5] + red[6] + red[7];
    float mean = s * (1.f / D_);
    float var  = ss * (1.f / D_) - mean * mean;
    float rstd = rsqrtf(var + 1e-5f);
    int c0 = tid * 8;
    __hip_bfloat16 ob[8];
#pragma unroll
    for (int j = 0; j < 8; ++j)
        ob[j] = __float2bfloat16((vv[j] - mean) * rstd * sc[c0 + j] + of[c0 + j]);
    *reinterpret_cast<uint4*>(out + (size_t)row * D_ + c0) = *reinterpret_cast<uint4*>(ob);
}

// ---------------------------------------------------------------------------
// 8-phase counted-vmcnt GEMM (schedule frozen). NEW r16: L2-blocked XCD
// mapping — each XCD owns a contiguous n-slab (nc = gx/8 cols), walked
// m-outer/n-inner: the nc B-panels (3-4 MB) stay L2-resident for the whole
// kernel; A-panels stream and are shared by adjacent concurrent blocks.
// EPI: 0 bf16; 1 f32+resid; 2 bf16+bias+gelu(fast); 3 f32+bias+resid;
//      4 bf16+rope
// ---------------------------------------------------------------------------
template<int EPI, int BM>
__global__ __launch_bounds__(512, 2) void gemm8p(
    const __hip_bfloat16* __restrict__ A, const __hip_bfloat16* __restrict__ BT,
    void* __restrict__ Cout, const float* __restrict__ bias,
    const float* __restrict__ resid, int M, int N, int K)
{
    constexpr int MFR = BM / 32;
    constexpr int AUL = BM / 128;
    constexpr int VMC = AUL + 2;
    __shared__ short As[2 * 2 * BM * 32];
    __shared__ short Bs[2 * 2 * 256 * 32];

    const int tid = threadIdx.x;
    const int wid = tid >> 6, lane = tid & 63;
    const int lo = lane & 15, hi = lane >> 4;
    const int wr = wid >> 2, wc = wid & 3;

    // L2-blocked XCD mapping (gx % 8 == 0 for all launches)
    const int gx  = gridDim.x;            // n-blocks
    const int nc  = gx >> 3;              // n-cols per XCD
    const int bid = blockIdx.y * gx + blockIdx.x;
    const int xcd = bid & 7;
    const int ii  = bid >> 3;
    const int m0  = (ii / nc) * BM;
    const int n0  = (xcd * nc + ii % nc) * 256;

    auto stageA = [&](int tt, int ks) {
#pragma unroll
        for (int l = 0; l < AUL; ++l) {
            int c    = l * 512 + tid;
            int row  = c >> 2, ksub = c & 3;
            int kc   = tt * 64 + ks * 32 + ((ksub ^ ((row >> 1) & 3)) << 3);
            int c0   = l * 512 + wid * 64;
            gload_lds16(A + (size_t)(m0 + row) * K + kc,
                        (char*)As + ((tt & 1) * 2 + ks) * (BM * 64) + c0 * 16);
        }
    };
    auto stageB = [&](int tt, int ks) {
#pragma unroll
        for (int l = 0; l < 2; ++l) {
            int c    = l * 512 + tid;
            int row  = c >> 2, ksub = c & 3;
            int kc   = tt * 64 + ks * 32 + ((ksub ^ ((row >> 1) & 3)) << 3);
            int c0   = l * 512 + wid * 64;
            gload_lds16(BT + (size_t)(n0 + row) * K + kc,
                        (char*)Bs + ((tt & 1) * 2 + ks) * 16384 + c0 * 16);
        }
    };

    const int fsw  = (hi ^ ((lo >> 1) & 3)) << 4;
    const int arow = wr * (BM / 2) + lo;
    const int brow = wc * 64 + lo;

    f32x4 acc[MFR][4] = {};
    const int NT = K >> 6;

    stageA(0, 0); stageB(0, 0); stageA(0, 1); stageB(0, 1);
    asm volatile("s_waitcnt vmcnt(%0)" :: "i"(VMC) : "memory");
    __builtin_amdgcn_s_barrier();

#define PHASE_MFMA(J)                                                         \
        __builtin_amdgcn_s_barrier();                                         \
        asm volatile("s_waitcnt lgkmcnt(0)" ::: "memory");                    \
        __builtin_amdgcn_s_setprio(1);                                        \
        _Pragma("unroll")                                                     \
        for (int m = 0; m < MFR; ++m) {                                       \
            acc[m][J]     = MFMA32(af[m], b0, acc[m][J]);                     \
            acc[m][J + 1] = MFMA32(af[m], b1, acc[m][J + 1]);                 \
        }                                                                     \
        __builtin_amdgcn_s_setprio(0);

#pragma unroll 2
    for (int t = 0; t < NT; ++t) {
        const int bsel = t & 1;
        const bool pf = (t + 1 < NT);
        const char* Ab = (const char*)As + bsel * (2 * BM * 64);
        const char* Bb = (const char*)Bs + bsel * 32768;
        bf16x8 af[MFR], b0, b1;

        // ---- P0: (ks0, nh0)
#pragma unroll
        for (int m = 0; m < MFR; ++m)
            af[m] = *reinterpret_cast<const bf16x8*>(Ab + (arow + m * 16) * 64 + fsw);
        b0 = *reinterpret_cast<const bf16x8*>(Bb + brow * 64 + fsw);
        b1 = *reinterpret_cast<const bf16x8*>(Bb + (brow + 16) * 64 + fsw);
        if (pf) stageA(t + 1, 0);
        PHASE_MFMA(0)
        __builtin_amdgcn_s_barrier();

        // ---- P1: (ks0, nh1)
        b0 = *reinterpret_cast<const bf16x8*>(Bb + (brow + 32) * 64 + fsw);
        b1 = *reinterpret_cast<const bf16x8*>(Bb + (brow + 48) * 64 + fsw);
        if (pf) stageB(t + 1, 0);
        PHASE_MFMA(2)
        asm volatile("s_waitcnt vmcnt(%0)" :: "i"(VMC) : "memory");
        __builtin_amdgcn_s_barrier();

        // ---- P2: (ks1, nh0)
#pragma unroll
        for (int m = 0; m < MFR; ++m)
            af[m] = *reinterpret_cast<const bf16x8*>(Ab + BM * 64 + (arow + m * 16) * 64 + fsw);
        b0 = *reinterpret_cast<const bf16x8*>(Bb + 16384 + brow * 64 + fsw);
        b1 = *reinterpret_cast<const bf16x8*>(Bb + 16384 + (brow + 16) * 64 + fsw);
        if (pf) stageA(t + 1, 1);
        PHASE_MFMA(0)
        __builtin_amdgcn_s_barrier();

        // ---- P3: (ks1, nh1)
        b0 = *reinterpret_cast<const bf16x8*>(Bb + 16384 + (brow + 32) * 64 + fsw);
        b1 = *reinterpret_cast<const bf16x8*>(Bb + 16384 + (brow + 48) * 64 + fsw);
        if (pf) stageB(t + 1, 1);
        PHASE_MFMA(2)
        asm volatile("s_waitcnt vmcnt(%0)" :: "i"(VMC) : "memory");
        __builtin_amdgcn_s_barrier();
    }
#undef PHASE_MFMA

    // ---- epilogue
    float* Cf = (float*)Cout;
    __hip_bfloat16* Cb = (__hip_bfloat16*)Cout;

    bool doRope = false;
    float invf[4];
    if (EPI == 4) {
        doRope = (n0 < 4096) && ((wc & 1) == 0);
        if (doRope) {
#pragma unroll
            for (int j = 0; j < 4; ++j) {
                int p = ((j >> 1) * 32 + (j & 1) * 16 + lo) >> 1;
                invf[j] = exp2f((float)p * -0.4152410118609203f);
            }
        }
    }

#pragma unroll
    for (int m = 0; m < MFR; ++m) {
        int rbase = m0 + wr * (BM / 2) + m * 16 + hi * 4;
#pragma unroll
        for (int j = 0; j < 4; ++j) {
            int col = n0 + wc * 64 + (j >> 1) * 32 + (j & 1) * 16 + lo;
            float bv = (EPI == 2 || EPI == 3) ? bias[col] : 0.f;
#pragma unroll
            for (int i = 0; i < 4; ++i) {
                size_t idx = (size_t)(rbase + i) * N + col;
                float v = acc[m][j][i];
                if (EPI == 4) {
                    if (doRope) {
                        float pv = __shfl_xor(v, 1);
                        int tt = (rbase + i) & (T_ - 1);
                        float fr = (float)tt * invf[j];
                        float cs, sn;
                        __sincosf(fr, &sn, &cs);
                        v = (lo & 1) ? (v * cs + pv * sn) : (v * cs - pv * sn);
                    }
                    Cb[idx] = __float2bfloat16(v);
                    continue;
                }
                if (EPI == 2 || EPI == 3) v += bv;
                if (EPI == 2) v = gelu_fast(v);
                if (EPI == 1 || EPI == 3) v += resid[idx];
                if (EPI == 0 || EPI == 2) Cb[idx] = __float2bfloat16(v);
                else                      Cf[idx] = v;
            }
        }
    }
}

// ---------------------------------------------------------------------------
// 2-phase 64KB-LDS GEMM (schedule frozen — WO and FF2) + r16 L2-blocked
// XCD mapping (nc = gx/8 n-cols per XCD, m-outer/n-inner).
// EPI: 5 f32 + bias + BF16 resid (FF2); 6 BF16 out + f32 resid (WO)
// ---------------------------------------------------------------------------
template<int EPI>
__global__ __launch_bounds__(512, 4) void gemmq(
    const __hip_bfloat16* __restrict__ A, const __hip_bfloat16* __restrict__ BT,
    void* __restrict__ Cout, const float* __restrict__ bias,
    const float* __restrict__ resid, int M, int N, int K)
{
    __shared__ short As[2 * 2 * 128 * 32];
    __shared__ short Bs[2 * 2 * 128 * 32];

    const int tid = threadIdx.x;
    const int wid = tid >> 6, lane = tid & 63;
    const int lo = lane & 15, hi = lane >> 4;
    const int wc = wid & 3;
    const int wr2 = wid >> 2;

    const int gx  = gridDim.x;
    const int nc  = gx >> 3;
    const int bid = blockIdx.y * gx + blockIdx.x;
    const int xcd = bid & 7;
    const int ii  = bid >> 3;
    const int m0  = (ii / nc) * 128;
    const int n0  = (xcd * nc + ii % nc) * 128;

    const int srow = tid >> 2, sslot = tid & 3;
    auto stageA = [&](int tt, int ks) {
        int kc = tt * 64 + ks * 32 + ((sslot ^ ((srow >> 1) & 3)) << 3);
        gload_lds16(A + (size_t)(m0 + srow) * K + kc,
                    (char*)As + ((tt & 1) * 2 + ks) * 8192 + wid * 1024);
    };
    auto stageB = [&](int tt, int ks) {
        int kc = tt * 64 + ks * 32 + ((sslot ^ ((srow >> 1) & 3)) << 3);
        gload_lds16(BT + (size_t)(n0 + srow) * K + kc,
                    (char*)Bs + ((tt & 1) * 2 + ks) * 8192 + wid * 1024);
    };

    const int fsw  = (hi ^ ((lo >> 1) & 3)) << 4;
    const int arow = wr2 * 64 + lo;
    const int brow = wc * 32 + lo;

    f32x4 acc[4][2] = {};
    const int NT = K >> 6;

    stageA(0, 0); stageB(0, 0); stageA(0, 1); stageB(0, 1);
    asm volatile("s_waitcnt vmcnt(2)" ::: "memory");
    __builtin_amdgcn_s_barrier();

#pragma unroll 2
    for (int t = 0; t < NT; ++t) {
        const int bsel = t & 1;
        const bool pf = (t + 1 < NT);
        const char* Ab = (const char*)As + bsel * 16384;
        const char* Bb = (const char*)Bs + bsel * 16384;

#pragma unroll
        for (int ks = 0; ks < 2; ++ks) {
            bf16x8 af[4], b0, b1;
#pragma unroll
            for (int m = 0; m < 4; ++m)
                af[m] = *reinterpret_cast<const bf16x8*>(
                    Ab + ks * 8192 + (arow + m * 16) * 64 + fsw);
            b0 = *reinterpret_cast<const bf16x8*>(Bb + ks * 8192 + brow * 64 + fsw);
            b1 = *reinterpret_cast<const bf16x8*>(Bb + ks * 8192 + (brow + 16) * 64 + fsw);
            if (pf) { stageA(t + 1, ks); stageB(t + 1, ks); }
            asm volatile("s_waitcnt lgkmcnt(0)" ::: "memory");
            __builtin_amdgcn_s_setprio(1);
#pragma unroll
            for (int m = 0; m < 4; ++m) {
                acc[m][0] = MFMA32(af[m], b0, acc[m][0]);
                acc[m][1] = MFMA32(af[m], b1, acc[m][1]);
            }
            __builtin_amdgcn_s_setprio(0);
            if (pf) asm volatile("s_waitcnt vmcnt(2)" ::: "memory");
            else    asm volatile("s_waitcnt vmcnt(0)" ::: "memory");
            __builtin_amdgcn_s_barrier();
        }
    }

    float* Cf = (float*)Cout;
    __hip_bfloat16* Cb = (__hip_bfloat16*)Cout;
    const __hip_bfloat16* residb = (const __hip_bfloat16*)resid;
#pragma unroll
    for (int m = 0; m < 4; ++m) {
        int rbase = m0 + wr2 * 64 + m * 16 + hi * 4;
#pragma unroll
        for (int j = 0; j < 2; ++j) {
            int col = n0 + wc * 32 + j * 16 + lo;
            float bv = (EPI == 3 || EPI == 5) ? bias[col] : 0.f;
#pragma unroll
            for (int i = 0; i < 4; ++i) {
                size_t idx = (size_t)(rbase + i) * N + col;
                float v = acc[m][j][i];
                if (EPI == 3 || EPI == 5) v += bv;
                if (EPI == 1 || EPI == 3 || EPI == 6) v += resid[idx];
                if (EPI == 5) v += __bfloat162float(residb[idx]);
                if (EPI == 6) Cb[idx] = __float2bfloat16(v);
                else          Cf[idx] = v;
            }
        }
    }
}

// ---------------------------------------------------------------------------
// Causal flash attention v7 (r14/r15, frozen)
// ---------------------------------------------------------------------------
__global__ __launch_bounds__(512) void attn_kernel(const __hip_bfloat16* __restrict__ qkv,
                                                   __hip_bfloat16* __restrict__ ctx)
{
    constexpr int LDQ = 3 * D_;

    int idx = blockIdx.y * 16 + blockIdx.x;
    int swz = (idx & 7) * 64 + (idx >> 3);
    const int bh  = swz >> 4;
    const int bxr = 15 - (swz & 15);
    const int b = bh >> 4, h = bh & 15;
    const int tq0 = bxr * 128;

    const int tid = threadIdx.x, wid = tid >> 6, lane = tid & 63;
    const int lo = lane & 15, hi = lane >> 4;
    const int t0 = tq0 + wid * 16;

    __shared__ short Ks[2][64 * 128];
    __shared__ short Vs[2][64 * 128];

    const __hip_bfloat16* qrow = qkv + (size_t)(b * T_ + t0 + lo) * LDQ + h * DH_;
    bf16x8 qf[4];
#pragma unroll
    for (int dk = 0; dk < 4; ++dk)
        qf[dk] = *reinterpret_cast<const bf16x8*>(qrow + dk * 32 + hi * 8);

    f32x4 octx[8] = {};
    float mreg = -1e30f, lreg = 0.f;

    const size_t kvrow0 = (size_t)(b * T_) * LDQ + h * DH_;
    const int nst = 2 * (bxr + 1);

    const uint vbase0 = (uint)(size_t)(__attribute__((address_space(3))) short*)&Vs[0][0]
                      + (uint)lane * 8u;

#define STAGE_K(s0v, buf)                                                     \
    do {                                                                      \
        _Pragma("unroll")                                                     \
        for (int i = 0; i < 2; ++i) {                                         \
            int c    = i * 512 + tid;                                         \
            int sr   = c >> 4;                                                \
            int cbs  = ((c & 15) * 16) ^ ((sr & 7) << 4);                     \
            gload_lds16(qkv + kvrow0 + (size_t)((s0v) + sr) * LDQ + D_ + (cbs >> 1), \
                        &Ks[buf][c * 8]);                                     \
        }                                                                     \
    } while (0)

#define STAGE_V(s0v, buf)                                                     \
    do {                                                                      \
        _Pragma("unroll")                                                     \
        for (int i = 0; i < 2; ++i) {                                         \
            int c  = i * 512 + tid;                                           \
            int s  = ((c >> 3) & 15) * 4 + ((c >> 1) & 3);                    \
            int d0 = (c >> 7) * 16 + (c & 1) * 8;                             \
            gload_lds16(qkv + kvrow0 + (size_t)((s0v) + s) * LDQ + 2 * D_ + d0, \
                        &Vs[buf][c * 8]);                                     \
        }                                                                     \
    } while (0)

    STAGE_K(0, 0);
    STAGE_V(0, 0);

    for (int st = 0; st < nst; ++st) {
        const int s0 = st * 64;
        const int cur = st & 1;
        __syncthreads();

        if (st + 1 < nst) {
            STAGE_K(s0 + 64, cur ^ 1);
            STAGE_V(s0 + 64, cur ^ 1);
        }

        f32x4 sfr[4] = {};
        __builtin_amdgcn_s_setprio(1);
#pragma unroll
        for (int f = 0; f < 4; ++f) {
            int srow = f * 16 + lo;
            int sw = (srow & 7) << 4;
#pragma unroll
            for (int dk = 0; dk < 4; ++dk) {
                bf16x8 kf = *reinterpret_cast<const bf16x8*>(
                    (const char*)&Ks[cur][0] + srow * 256 + ((dk * 64 + hi * 16) ^ sw));
                sfr[f] = MFMA32(kf, qf[dk], sfr[f]);
            }
        }
        __builtin_amdgcn_s_setprio(0);

        const float qsc = 0.08838834764831845f;
#pragma unroll
        for (int f = 0; f < 4; ++f)
#pragma unroll
            for (int i = 0; i < 4; ++i)
                sfr[f][i] *= qsc;
        if (st >= nst - 2) {
#pragma unroll
            for (int f = 0; f < 4; ++f)
#pragma unroll
                for (int i = 0; i < 4; ++i)
                    if (s0 + f * 16 + hi * 4 + i > t0 + lo) sfr[f][i] = -1e30f;
        }

        float mx = -1e30f;
#pragma unroll
        for (int f = 0; f < 4; ++f)
#pragma unroll
            for (int i = 0; i < 4; ++i)
                mx = fmaxf(mx, sfr[f][i]);
        mx = fmaxf(mx, __shfl_xor(mx, 16));
        mx = fmaxf(mx, __shfl_xor(mx, 32));

        if (!__all(mx - mreg <= 8.f)) {
            float mn = fmaxf(mreg, mx);
            float ps = __expf(mreg - mn);
            mreg = mn;
            lreg *= ps;
            float psq[4];
#pragma unroll
            for (int i = 0; i < 4; ++i)
                psq[i] = __shfl(ps, hi * 4 + i);
#pragma unroll
            for (int f8 = 0; f8 < 8; ++f8)
#pragma unroll
                for (int i = 0; i < 4; ++i)
                    octx[f8][i] *= psq[i];
        }

        float sum = 0.f;
#pragma unroll
        for (int f = 0; f < 4; ++f)
#pragma unroll
            for (int i = 0; i < 4; ++i) {
                sfr[f][i] = __expf(sfr[f][i] - mreg);
                sum += sfr[f][i];
            }
        sum += __shfl_xor(sum, 16);
        sum += __shfl_xor(sum, 32);
        lreg += sum;

        const uint vaddr = vbase0 + (uint)(cur << 14);
#pragma unroll
        for (int ks = 0; ks < 2; ++ks) {
            union { bf16x8 v; short s[8]; } pa;
#pragma unroll
            for (int j = 0; j < 4; ++j) {
                pa.s[j]     = f2bf(sfr[2 * ks][j]);
                pa.s[j + 4] = f2bf(sfr[2 * ks + 1][j]);
            }
            unsigned long long tr[8][2];
#pragma unroll
            for (int f8 = 0; f8 < 8; ++f8) {
                asm volatile("ds_read_b64_tr_b16 %0, %2 offset:%3\n\t"
                             "ds_read_b64_tr_b16 %1, %2 offset:%4"
                             : "=&v"(tr[f8][0]), "=&v"(tr[f8][1])
                             : "v"(vaddr),
                               "i"((f8 * 16 + 8 * ks) * 128),
                               "i"((f8 * 16 + 8 * ks + 4) * 128));
            }
            asm volatile("s_waitcnt lgkmcnt(0)" ::: "memory");
            __builtin_amdgcn_sched_barrier(0);
            __builtin_amdgcn_s_setprio(1);
#pragma unroll
            for (int f8 = 0; f8 < 8; ++f8) {
                union { bf16x8 v; unsigned long long q[2]; } vb;
                vb.q[0] = tr[f8][0];
                vb.q[1] = tr[f8][1];
                octx[f8] = MFMA32(pa.v, vb.v, octx[f8]);
            }
            __builtin_amdgcn_s_setprio(0);
        }
    }
#undef STAGE_K
#undef STAGE_V

    float linv[4];
#pragma unroll
    for (int i = 0; i < 4; ++i)
        linv[i] = 1.f / __shfl(lreg, hi * 4 + i);
#pragma unroll
    for (int i = 0; i < 4; ++i) {
        size_t rb = (size_t)(b * T_ + t0 + hi * 4 + i) * D_ + h * DH_;
#pragma unroll
        for (int f8 = 0; f8 < 8; ++f8)
            ctx[rb + f8 * 16 + lo] = __float2bfloat16(octx[f8][i] * linv[i]);
    }
}

// ---------------------------------------------------------------------------
extern "C" void kernel_launch(void* const* d_in, const int* in_sizes, int n_in,
                              void* d_out, int out_size, void* d_ws, size_t ws_size,
                              hipStream_t stream)
{
    (void)in_sizes; (void)n_in; (void)out_size; (void)ws_size;
    const float* x   = (const float*)d_in[0];
    const float* lns = (const float*)d_in[1];
    const float* lno = (const float*)d_in[2];
    const float* wq  = (const float*)d_in[3];
    const float* wk  = (const float*)d_in[4];
    const float* wv  = (const float*)d_in[5];
    const float* wo  = (const float*)d_in[6];
    const float* w1  = (const float*)d_in[7];
    const float* b1  = (const float*)d_in[8];
    const float* w2  = (const float*)d_in[9];
    const float* b2  = (const float*)d_in[10];
    float* out = (float*)d_out;

    char* ws = (char*)d_ws;
    __hip_bfloat16* wqkvT = (__hip_bfloat16*)(ws);                 // 6144x2048 bf16
    __hip_bfloat16* woT   = (__hip_bfloat16*)(ws + 25165824);      // 2048x2048
    __hip_bfloat16* w1T   = (__hip_bfloat16*)(ws + 33554432);      // 8192x2048
    __hip_bfloat16* w2T   = (__hip_bfloat16*)(ws + 67108864);      // 2048x8192
    __hip_bfloat16* xn    = (__hip_bfloat16*)(ws + 100663296);     // 4096x2048 (xn / xn2)
    __hip_bfloat16* qkv   = (__hip_bfloat16*)(ws + 117440512);     // 4096x6144
    __hip_bfloat16* hbuf  = qkv;                                   // 4096x8192 (aliases qkv+ctx)
    __hip_bfloat16* ctx   = (__hip_bfloat16*)(ws + 167772160);     // 4096x2048
    __hip_bfloat16* x1b   = (__hip_bfloat16*)(ws + 184549376);     // 4096x2048 bf16 (x1)

    transpose_cvt4<<<dim3(32, 64, 4), 256, 0, stream>>>(wq, wk, wv, wo, wqkvT, woT);
    transpose_cvt<<<dim3(128, 64), 256, 0, stream>>>(w1, w1T, 2048, 8192, 2048, 0);
    transpose_cvt<<<dim3(32, 256), 256, 0, stream>>>(w2, w2T, 8192, 2048, 8192, 0);

    ln_kernel<<<4096, 256, 0, stream>>>(x, lns, lno, xn);
    gemm8p<4, 128><<<dim3(24, 32), 512, 0, stream>>>(xn, wqkvT, qkv, nullptr, nullptr, 4096, 6144, 2048);
    attn_kernel<<<dim3(16, 32), 512, 0, stream>>>(qkv, ctx);
    gemmq<6><<<dim3(16, 32), 512, 0, stream>>>(ctx, woT, x1b, nullptr, x, 4096, 2048, 2048);
    ln_bf16_kernel<<<4096, 256, 0, stream>>>(x1b, lns, lno, xn);
    gemm8p<2, 256><<<dim3(32, 16), 512, 0, stream>>>(xn, w1T, hbuf, b1, nullptr, 4096, 8192, 2048);
    gemmq<5><<<dim3(16, 32), 512, 0, stream>>>(hbuf, w2T, out, b2, (const float*)x1b, 4096, 2048, 8192);
}

// Round 17
// 650.934 us; speedup vs baseline: 1.0260x; 1.0260x over previous
//
#include <hip/hip_runtime.h>
#include <hip/hip_bf16.h>

#define B_   2
#define T_   2048
#define D_   2048
#define H_   16
#define DH_  128
#define DFF_ 8192

typedef __attribute__((ext_vector_type(8))) short bf16x8;
typedef __attribute__((ext_vector_type(4))) float f32x4;

__device__ __forceinline__ short f2bf(float f) {
    __hip_bfloat16 h = __float2bfloat16(f);
    return *reinterpret_cast<short*>(&h);
}

__device__ __forceinline__ void gload_lds16(const void* g, void* l) {
    __builtin_amdgcn_global_load_lds(
        (const __attribute__((address_space(1))) void*)g,
        (__attribute__((address_space(3))) void*)l,
        16, 0, 0);
}

// gelu_tanh(x) = 0.5x(1+tanh(z)) == x/(1+exp(-2z)); exact identity.
__device__ __forceinline__ float gelu_fast(float x) {
    float z = 0.7978845608028654f * (x + 0.044715f * x * x * x);
    return x / (1.f + __expf(-2.f * z));
}

#define MFMA32(a, b, c) __builtin_amdgcn_mfma_f32_16x16x32_bf16((a), (b), (c), 0, 0, 0)

// ---------------------------------------------------------------------------
// Transpose + f32->bf16 convert (frozen; used for w1, w2)
// ---------------------------------------------------------------------------
__global__ __launch_bounds__(256) void transpose_cvt(const float* __restrict__ in,
                                                     __hip_bfloat16* __restrict__ out,
                                                     int K, int N, int out_ld, int out_row0)
{
    __shared__ float t[32][65];
    const int n0 = blockIdx.x * 64, k0 = blockIdx.y * 32;
    const int tid = threadIdx.x;
    {
        int kr = tid >> 4;
        int nc = (tid & 15) * 4;
        const float* src = in + (size_t)(k0 + kr) * N + n0 + nc;
        float4 a = *reinterpret_cast<const float4*>(src);
        float4 b = *reinterpret_cast<const float4*>(src + (size_t)16 * N);
        t[kr][nc] = a.x; t[kr][nc + 1] = a.y; t[kr][nc + 2] = a.z; t[kr][nc + 3] = a.w;
        t[kr + 16][nc] = b.x; t[kr + 16][nc + 1] = b.y; t[kr + 16][nc + 2] = b.z; t[kr + 16][nc + 3] = b.w;
    }
    __syncthreads();
    {
        int n  = tid >> 2;
        int kc = (tid & 3) * 8;
        __hip_bfloat16 ob[8];
#pragma unroll
        for (int j = 0; j < 8; ++j) ob[j] = __float2bfloat16(t[kc + j][n]);
        *reinterpret_cast<uint4*>(out + (size_t)(out_row0 + n0 + n) * out_ld + k0 + kc) =
            *reinterpret_cast<uint4*>(ob);
    }
}

// ---------------------------------------------------------------------------
// Merged 4x square (2048^2) weight transpose: z selects wq/wk/wv/wo.
// ---------------------------------------------------------------------------
__global__ __launch_bounds__(256) void transpose_cvt4(
    const float* __restrict__ wq, const float* __restrict__ wk,
    const float* __restrict__ wv, const float* __restrict__ wo,
    __hip_bfloat16* __restrict__ oqkv, __hip_bfloat16* __restrict__ owo)
{
    const int z = blockIdx.z;
    const float* in = (z == 0) ? wq : (z == 1) ? wk : (z == 2) ? wv : wo;
    __hip_bfloat16* out = (z < 3) ? (oqkv + (size_t)z * 2048 * 2048) : owo;

    __shared__ float t[32][65];
    const int n0 = blockIdx.x * 64, k0 = blockIdx.y * 32;
    const int tid = threadIdx.x;
    {
        int kr = tid >> 4;
        int nc = (tid & 15) * 4;
        const float* src = in + (size_t)(k0 + kr) * 2048 + n0 + nc;
        float4 a = *reinterpret_cast<const float4*>(src);
        float4 b = *reinterpret_cast<const float4*>(src + (size_t)16 * 2048);
        t[kr][nc] = a.x; t[kr][nc + 1] = a.y; t[kr][nc + 2] = a.z; t[kr][nc + 3] = a.w;
        t[kr + 16][nc] = b.x; t[kr + 16][nc + 1] = b.y; t[kr + 16][nc + 2] = b.z; t[kr + 16][nc + 3] = b.w;
    }
    __syncthreads();
    {
        int n  = tid >> 2;
        int kc = (tid & 3) * 8;
        __hip_bfloat16 ob[8];
#pragma unroll
        for (int j = 0; j < 8; ++j) ob[j] = __float2bfloat16(t[kc + j][n]);
        *reinterpret_cast<uint4*>(out + (size_t)(n0 + n) * 2048 + k0 + kc) =
            *reinterpret_cast<uint4*>(ob);
    }
}

// ---------------------------------------------------------------------------
// LayerNorm, f32 input (frozen; LN1)
// ---------------------------------------------------------------------------
__global__ __launch_bounds__(256) void ln_kernel(const float* __restrict__ x,
                                                 const float* __restrict__ sc,
                                                 const float* __restrict__ of,
                                                 __hip_bfloat16* __restrict__ out)
{
    int row = blockIdx.x, tid = threadIdx.x;
    const float* xr = x + (size_t)row * D_;
    float4 v0 = reinterpret_cast<const float4*>(xr)[tid * 2];
    float4 v1 = reinterpret_cast<const float4*>(xr)[tid * 2 + 1];
    float vv[8] = {v0.x, v0.y, v0.z, v0.w, v1.x, v1.y, v1.z, v1.w};
    float s = 0.f, ss = 0.f;
#pragma unroll
    for (int j = 0; j < 8; ++j) { s += vv[j]; ss += vv[j] * vv[j]; }
    for (int o = 32; o; o >>= 1) { s += __shfl_down(s, o); ss += __shfl_down(ss, o); }
    __shared__ float red[8];
    int wid = tid >> 6, lane = tid & 63;
    if (!lane) { red[wid] = s; red[4 + wid] = ss; }
    __syncthreads();
    s  = red[0] + red[1] + red[2] + red[3];
    ss = red[4] + red[5] + red[6] + red[7];
    float mean = s * (1.f / D_);
    float var  = ss * (1.f / D_) - mean * mean;
    float rstd = rsqrtf(var + 1e-5f);
    int c0 = tid * 8;
    __hip_bfloat16 ob[8];
#pragma unroll
    for (int j = 0; j < 8; ++j)
        ob[j] = __float2bfloat16((vv[j] - mean) * rstd * sc[c0 + j] + of[c0 + j]);
    *reinterpret_cast<uint4*>(out + (size_t)row * D_ + c0) = *reinterpret_cast<uint4*>(ob);
}

// ---------------------------------------------------------------------------
// LayerNorm, bf16 input (LN2; frozen)
// ---------------------------------------------------------------------------
__global__ __launch_bounds__(256) void ln_bf16_kernel(const __hip_bfloat16* __restrict__ x,
                                                      const float* __restrict__ sc,
                                                      const float* __restrict__ of,
                                                      __hip_bfloat16* __restrict__ out)
{
    int row = blockIdx.x, tid = threadIdx.x;
    uint4 u = *reinterpret_cast<const uint4*>(x + (size_t)row * D_ + tid * 8);
    const unsigned short* us = reinterpret_cast<const unsigned short*>(&u);
    float vv[8];
#pragma unroll
    for (int j = 0; j < 8; ++j)
        vv[j] = __uint_as_float((unsigned)us[j] << 16);
    float s = 0.f, ss = 0.f;
#pragma unroll
    for (int j = 0; j < 8; ++j) { s += vv[j]; ss += vv[j] * vv[j]; }
    for (int o = 32; o; o >>= 1) { s += __shfl_down(s, o); ss += __shfl_down(ss, o); }
    __shared__ float red[8];
    int wid = tid >> 6, lane = tid & 63;
    if (!lane) { red[wid] = s; red[4 + wid] = ss; }
    __syncthreads();
    s  = red[0] + red[1] + red[2] + red[3];
    ss = red[4] + red[5] + red[6] + red[7];
    float mean = s * (1.f / D_);
    float var  = ss * (1.f / D_) - mean * mean;
    float rstd = rsqrtf(var + 1e-5f);
    int c0 = tid * 8;
    __hip_bfloat16 ob[8];
#pragma unroll
    for (int j = 0; j < 8; ++j)
        ob[j] = __float2bfloat16((vv[j] - mean) * rstd * sc[c0 + j] + of[c0 + j]);
    *reinterpret_cast<uint4*>(out + (size_t)row * D_ + c0) = *reinterpret_cast<uint4*>(ob);
}

// ---------------------------------------------------------------------------
// 8-phase counted-vmcnt GEMM (schedule frozen). L2-blocked XCD mapping
// (kept from r16 — helps at 1 block/CU where block ordering creates temporal
// locality: each XCD owns an n-slab of nc = gx/8 cols, walked m-outer/
// n-inner; the nc B-panels stay L2-resident).
// EPI: 0 bf16; 2 bf16+bias+gelu(fast); 4 bf16+rope
// ---------------------------------------------------------------------------
template<int EPI, int BM>
__global__ __launch_bounds__(512, 2) void gemm8p(
    const __hip_bfloat16* __restrict__ A, const __hip_bfloat16* __restrict__ BT,
    void* __restrict__ Cout, const float* __restrict__ bias,
    const float* __restrict__ resid, int M, int N, int K)
{
    constexpr int MFR = BM / 32;
    constexpr int AUL = BM / 128;
    constexpr int VMC = AUL + 2;
    __shared__ short As[2 * 2 * BM * 32];
    __shared__ short Bs[2 * 2 * 256 * 32];

    const int tid = threadIdx.x;
    const int wid = tid >> 6, lane = tid & 63;
    const int lo = lane & 15, hi = lane >> 4;
    const int wr = wid >> 2, wc = wid & 3;

    // L2-blocked XCD mapping (gx % 8 == 0 for all launches)
    const int gx  = gridDim.x;            // n-blocks
    const int nc  = gx >> 3;              // n-cols per XCD
    const int bid = blockIdx.y * gx + blockIdx.x;
    const int xcd = bid & 7;
    const int ii  = bid >> 3;
    const int m0  = (ii / nc) * BM;
    const int n0  = (xcd * nc + ii % nc) * 256;

    auto stageA = [&](int tt, int ks) {
#pragma unroll
        for (int l = 0; l < AUL; ++l) {
            int c    = l * 512 + tid;
            int row  = c >> 2, ksub = c & 3;
            int kc   = tt * 64 + ks * 32 + ((ksub ^ ((row >> 1) & 3)) << 3);
            int c0   = l * 512 + wid * 64;
            gload_lds16(A + (size_t)(m0 + row) * K + kc,
                        (char*)As + ((tt & 1) * 2 + ks) * (BM * 64) + c0 * 16);
        }
    };
    auto stageB = [&](int tt, int ks) {
#pragma unroll
        for (int l = 0; l < 2; ++l) {
            int c    = l * 512 + tid;
            int row  = c >> 2, ksub = c & 3;
            int kc   = tt * 64 + ks * 32 + ((ksub ^ ((row >> 1) & 3)) << 3);
            int c0   = l * 512 + wid * 64;
            gload_lds16(BT + (size_t)(n0 + row) * K + kc,
                        (char*)Bs + ((tt & 1) * 2 + ks) * 16384 + c0 * 16);
        }
    };

    const int fsw  = (hi ^ ((lo >> 1) & 3)) << 4;
    const int arow = wr * (BM / 2) + lo;
    const int brow = wc * 64 + lo;

    f32x4 acc[MFR][4] = {};
    const int NT = K >> 6;

    stageA(0, 0); stageB(0, 0); stageA(0, 1); stageB(0, 1);
    asm volatile("s_waitcnt vmcnt(%0)" :: "i"(VMC) : "memory");
    __builtin_amdgcn_s_barrier();

#define PHASE_MFMA(J)                                                         \
        __builtin_amdgcn_s_barrier();                                         \
        asm volatile("s_waitcnt lgkmcnt(0)" ::: "memory");                    \
        __builtin_amdgcn_s_setprio(1);                                        \
        _Pragma("unroll")                                                     \
        for (int m = 0; m < MFR; ++m) {                                       \
            acc[m][J]     = MFMA32(af[m], b0, acc[m][J]);                     \
            acc[m][J + 1] = MFMA32(af[m], b1, acc[m][J + 1]);                 \
        }                                                                     \
        __builtin_amdgcn_s_setprio(0);

#pragma unroll 2
    for (int t = 0; t < NT; ++t) {
        const int bsel = t & 1;
        const bool pf = (t + 1 < NT);
        const char* Ab = (const char*)As + bsel * (2 * BM * 64);
        const char* Bb = (const char*)Bs + bsel * 32768;
        bf16x8 af[MFR], b0, b1;

        // ---- P0: (ks0, nh0)
#pragma unroll
        for (int m = 0; m < MFR; ++m)
            af[m] = *reinterpret_cast<const bf16x8*>(Ab + (arow + m * 16) * 64 + fsw);
        b0 = *reinterpret_cast<const bf16x8*>(Bb + brow * 64 + fsw);
        b1 = *reinterpret_cast<const bf16x8*>(Bb + (brow + 16) * 64 + fsw);
        if (pf) stageA(t + 1, 0);
        PHASE_MFMA(0)
        __builtin_amdgcn_s_barrier();

        // ---- P1: (ks0, nh1)
        b0 = *reinterpret_cast<const bf16x8*>(Bb + (brow + 32) * 64 + fsw);
        b1 = *reinterpret_cast<const bf16x8*>(Bb + (brow + 48) * 64 + fsw);
        if (pf) stageB(t + 1, 0);
        PHASE_MFMA(2)
        asm volatile("s_waitcnt vmcnt(%0)" :: "i"(VMC) : "memory");
        __builtin_amdgcn_s_barrier();

        // ---- P2: (ks1, nh0)
#pragma unroll
        for (int m = 0; m < MFR; ++m)
            af[m] = *reinterpret_cast<const bf16x8*>(Ab + BM * 64 + (arow + m * 16) * 64 + fsw);
        b0 = *reinterpret_cast<const bf16x8*>(Bb + 16384 + brow * 64 + fsw);
        b1 = *reinterpret_cast<const bf16x8*>(Bb + 16384 + (brow + 16) * 64 + fsw);
        if (pf) stageA(t + 1, 1);
        PHASE_MFMA(0)
        __builtin_amdgcn_s_barrier();

        // ---- P3: (ks1, nh1)
        b0 = *reinterpret_cast<const bf16x8*>(Bb + 16384 + (brow + 32) * 64 + fsw);
        b1 = *reinterpret_cast<const bf16x8*>(Bb + 16384 + (brow + 48) * 64 + fsw);
        if (pf) stageB(t + 1, 1);
        PHASE_MFMA(2)
        asm volatile("s_waitcnt vmcnt(%0)" :: "i"(VMC) : "memory");
        __builtin_amdgcn_s_barrier();
    }
#undef PHASE_MFMA

    // ---- epilogue
    float* Cf = (float*)Cout;
    __hip_bfloat16* Cb = (__hip_bfloat16*)Cout;

    bool doRope = false;
    float invf[4];
    if (EPI == 4) {
        doRope = (n0 < 4096) && ((wc & 1) == 0);
        if (doRope) {
#pragma unroll
            for (int j = 0; j < 4; ++j) {
                int p = ((j >> 1) * 32 + (j & 1) * 16 + lo) >> 1;
                invf[j] = exp2f((float)p * -0.4152410118609203f);
            }
        }
    }

#pragma unroll
    for (int m = 0; m < MFR; ++m) {
        int rbase = m0 + wr * (BM / 2) + m * 16 + hi * 4;
#pragma unroll
        for (int j = 0; j < 4; ++j) {
            int col = n0 + wc * 64 + (j >> 1) * 32 + (j & 1) * 16 + lo;
            float bv = (EPI == 2 || EPI == 3) ? bias[col] : 0.f;
#pragma unroll
            for (int i = 0; i < 4; ++i) {
                size_t idx = (size_t)(rbase + i) * N + col;
                float v = acc[m][j][i];
                if (EPI == 4) {
                    if (doRope) {
                        float pv = __shfl_xor(v, 1);
                        int tt = (rbase + i) & (T_ - 1);
                        float fr = (float)tt * invf[j];
                        float cs, sn;
                        __sincosf(fr, &sn, &cs);
                        v = (lo & 1) ? (v * cs + pv * sn) : (v * cs - pv * sn);
                    }
                    Cb[idx] = __float2bfloat16(v);
                    continue;
                }
                if (EPI == 2 || EPI == 3) v += bv;
                if (EPI == 2) v = gelu_fast(v);
                if (EPI == 1 || EPI == 3) v += resid[idx];
                if (EPI == 0 || EPI == 2) Cb[idx] = __float2bfloat16(v);
                else                      Cf[idx] = v;
            }
        }
    }
}

// ---------------------------------------------------------------------------
// 2-phase 64KB-LDS GEMM (schedule frozen — WO and FF2). REVERTED to the r15
// bijective XCD swizzle: at 2 blocks/CU all per-XCD blocks are co-resident,
// so m-outer ordering gives no temporal locality (r16: FF2 FETCH 364 MB,
// regression); the interleaved swizzle measured better.
// EPI: 5 f32 + bias + BF16 resid (FF2); 6 BF16 out + f32 resid (WO)
// ---------------------------------------------------------------------------
template<int EPI>
__global__ __launch_bounds__(512, 4) void gemmq(
    const __hip_bfloat16* __restrict__ A, const __hip_bfloat16* __restrict__ BT,
    void* __restrict__ Cout, const float* __restrict__ bias,
    const float* __restrict__ resid, int M, int N, int K)
{
    __shared__ short As[2 * 2 * 128 * 32];
    __shared__ short Bs[2 * 2 * 128 * 32];

    const int tid = threadIdx.x;
    const int wid = tid >> 6, lane = tid & 63;
    const int lo = lane & 15, hi = lane >> 4;
    const int wc = wid & 3;
    const int wr2 = wid >> 2;

    // r15 bijective XCD swizzle
    const int gx  = gridDim.x;
    const int nwg = gx * gridDim.y;
    const int bid = blockIdx.y * gx + blockIdx.x;
    const int swz = (bid & 7) * (nwg >> 3) + (bid >> 3);
    const int m0  = (swz / gx) * 128;
    const int n0  = (swz % gx) * 128;

    const int srow = tid >> 2, sslot = tid & 3;
    auto stageA = [&](int tt, int ks) {
        int kc = tt * 64 + ks * 32 + ((sslot ^ ((srow >> 1) & 3)) << 3);
        gload_lds16(A + (size_t)(m0 + srow) * K + kc,
                    (char*)As + ((tt & 1) * 2 + ks) * 8192 + wid * 1024);
    };
    auto stageB = [&](int tt, int ks) {
        int kc = tt * 64 + ks * 32 + ((sslot ^ ((srow >> 1) & 3)) << 3);
        gload_lds16(BT + (size_t)(n0 + srow) * K + kc,
                    (char*)Bs + ((tt & 1) * 2 + ks) * 8192 + wid * 1024);
    };

    const int fsw  = (hi ^ ((lo >> 1) & 3)) << 4;
    const int arow = wr2 * 64 + lo;
    const int brow = wc * 32 + lo;

    f32x4 acc[4][2] = {};
    const int NT = K >> 6;

    stageA(0, 0); stageB(0, 0); stageA(0, 1); stageB(0, 1);
    asm volatile("s_waitcnt vmcnt(2)" ::: "memory");
    __builtin_amdgcn_s_barrier();

#pragma unroll 2
    for (int t = 0; t < NT; ++t) {
        const int bsel = t & 1;
        const bool pf = (t + 1 < NT);
        const char* Ab = (const char*)As + bsel * 16384;
        const char* Bb = (const char*)Bs + bsel * 16384;

#pragma unroll
        for (int ks = 0; ks < 2; ++ks) {
            bf16x8 af[4], b0, b1;
#pragma unroll
            for (int m = 0; m < 4; ++m)
                af[m] = *reinterpret_cast<const bf16x8*>(
                    Ab + ks * 8192 + (arow + m * 16) * 64 + fsw);
            b0 = *reinterpret_cast<const bf16x8*>(Bb + ks * 8192 + brow * 64 + fsw);
            b1 = *reinterpret_cast<const bf16x8*>(Bb + ks * 8192 + (brow + 16) * 64 + fsw);
            if (pf) { stageA(t + 1, ks); stageB(t + 1, ks); }
            asm volatile("s_waitcnt lgkmcnt(0)" ::: "memory");
            __builtin_amdgcn_s_setprio(1);
#pragma unroll
            for (int m = 0; m < 4; ++m) {
                acc[m][0] = MFMA32(af[m], b0, acc[m][0]);
                acc[m][1] = MFMA32(af[m], b1, acc[m][1]);
            }
            __builtin_amdgcn_s_setprio(0);
            if (pf) asm volatile("s_waitcnt vmcnt(2)" ::: "memory");
            else    asm volatile("s_waitcnt vmcnt(0)" ::: "memory");
            __builtin_amdgcn_s_barrier();
        }
    }

    float* Cf = (float*)Cout;
    __hip_bfloat16* Cb = (__hip_bfloat16*)Cout;
    const __hip_bfloat16* residb = (const __hip_bfloat16*)resid;
#pragma unroll
    for (int m = 0; m < 4; ++m) {
        int rbase = m0 + wr2 * 64 + m * 16 + hi * 4;
#pragma unroll
        for (int j = 0; j < 2; ++j) {
            int col = n0 + wc * 32 + j * 16 + lo;
            float bv = (EPI == 3 || EPI == 5) ? bias[col] : 0.f;
#pragma unroll
            for (int i = 0; i < 4; ++i) {
                size_t idx = (size_t)(rbase + i) * N + col;
                float v = acc[m][j][i];
                if (EPI == 3 || EPI == 5) v += bv;
                if (EPI == 1 || EPI == 3 || EPI == 6) v += resid[idx];
                if (EPI == 5) v += __bfloat162float(residb[idx]);
                if (EPI == 6) Cb[idx] = __float2bfloat16(v);
                else          Cf[idx] = v;
            }
        }
    }
}

// ---------------------------------------------------------------------------
// Causal flash attention v7 (r14/r15, frozen)
// ---------------------------------------------------------------------------
__global__ __launch_bounds__(512) void attn_kernel(const __hip_bfloat16* __restrict__ qkv,
                                                   __hip_bfloat16* __restrict__ ctx)
{
    constexpr int LDQ = 3 * D_;

    int idx = blockIdx.y * 16 + blockIdx.x;
    int swz = (idx & 7) * 64 + (idx >> 3);
    const int bh  = swz >> 4;
    const int bxr = 15 - (swz & 15);
    const int b = bh >> 4, h = bh & 15;
    const int tq0 = bxr * 128;

    const int tid = threadIdx.x, wid = tid >> 6, lane = tid & 63;
    const int lo = lane & 15, hi = lane >> 4;
    const int t0 = tq0 + wid * 16;

    __shared__ short Ks[2][64 * 128];
    __shared__ short Vs[2][64 * 128];

    const __hip_bfloat16* qrow = qkv + (size_t)(b * T_ + t0 + lo) * LDQ + h * DH_;
    bf16x8 qf[4];
#pragma unroll
    for (int dk = 0; dk < 4; ++dk)
        qf[dk] = *reinterpret_cast<const bf16x8*>(qrow + dk * 32 + hi * 8);

    f32x4 octx[8] = {};
    float mreg = -1e30f, lreg = 0.f;

    const size_t kvrow0 = (size_t)(b * T_) * LDQ + h * DH_;
    const int nst = 2 * (bxr + 1);

    const uint vbase0 = (uint)(size_t)(__attribute__((address_space(3))) short*)&Vs[0][0]
                      + (uint)lane * 8u;

#define STAGE_K(s0v, buf)                                                     \
    do {                                                                      \
        _Pragma("unroll")                                                     \
        for (int i = 0; i < 2; ++i) {                                         \
            int c    = i * 512 + tid;                                         \
            int sr   = c >> 4;                                                \
            int cbs  = ((c & 15) * 16) ^ ((sr & 7) << 4);                     \
            gload_lds16(qkv + kvrow0 + (size_t)((s0v) + sr) * LDQ + D_ + (cbs >> 1), \
                        &Ks[buf][c * 8]);                                     \
        }                                                                     \
    } while (0)

#define STAGE_V(s0v, buf)                                                     \
    do {                                                                      \
        _Pragma("unroll")                                                     \
        for (int i = 0; i < 2; ++i) {                                         \
            int c  = i * 512 + tid;                                           \
            int s  = ((c >> 3) & 15) * 4 + ((c >> 1) & 3);                    \
            int d0 = (c >> 7) * 16 + (c & 1) * 8;                             \
            gload_lds16(qkv + kvrow0 + (size_t)((s0v) + s) * LDQ + 2 * D_ + d0, \
                        &Vs[buf][c * 8]);                                     \
        }                                                                     \
    } while (0)

    STAGE_K(0, 0);
    STAGE_V(0, 0);

    for (int st = 0; st < nst; ++st) {
        const int s0 = st * 64;
        const int cur = st & 1;
        __syncthreads();

        if (st + 1 < nst) {
            STAGE_K(s0 + 64, cur ^ 1);
            STAGE_V(s0 + 64, cur ^ 1);
        }

        f32x4 sfr[4] = {};
        __builtin_amdgcn_s_setprio(1);
#pragma unroll
        for (int f = 0; f < 4; ++f) {
            int srow = f * 16 + lo;
            int sw = (srow & 7) << 4;
#pragma unroll
            for (int dk = 0; dk < 4; ++dk) {
                bf16x8 kf = *reinterpret_cast<const bf16x8*>(
                    (const char*)&Ks[cur][0] + srow * 256 + ((dk * 64 + hi * 16) ^ sw));
                sfr[f] = MFMA32(kf, qf[dk], sfr[f]);
            }
        }
        __builtin_amdgcn_s_setprio(0);

        const float qsc = 0.08838834764831845f;
#pragma unroll
        for (int f = 0; f < 4; ++f)
#pragma unroll
            for (int i = 0; i < 4; ++i)
                sfr[f][i] *= qsc;
        if (st >= nst - 2) {
#pragma unroll
            for (int f = 0; f < 4; ++f)
#pragma unroll
                for (int i = 0; i < 4; ++i)
                    if (s0 + f * 16 + hi * 4 + i > t0 + lo) sfr[f][i] = -1e30f;
        }

        float mx = -1e30f;
#pragma unroll
        for (int f = 0; f < 4; ++f)
#pragma unroll
            for (int i = 0; i < 4; ++i)
                mx = fmaxf(mx, sfr[f][i]);
        mx = fmaxf(mx, __shfl_xor(mx, 16));
        mx = fmaxf(mx, __shfl_xor(mx, 32));

        if (!__all(mx - mreg <= 8.f)) {
            float mn = fmaxf(mreg, mx);
            float ps = __expf(mreg - mn);
            mreg = mn;
            lreg *= ps;
            float psq[4];
#pragma unroll
            for (int i = 0; i < 4; ++i)
                psq[i] = __shfl(ps, hi * 4 + i);
#pragma unroll
            for (int f8 = 0; f8 < 8; ++f8)
#pragma unroll
                for (int i = 0; i < 4; ++i)
                    octx[f8][i] *= psq[i];
        }

        float sum = 0.f;
#pragma unroll
        for (int f = 0; f < 4; ++f)
#pragma unroll
            for (int i = 0; i < 4; ++i) {
                sfr[f][i] = __expf(sfr[f][i] - mreg);
                sum += sfr[f][i];
            }
        sum += __shfl_xor(sum, 16);
        sum += __shfl_xor(sum, 32);
        lreg += sum;

        const uint vaddr = vbase0 + (uint)(cur << 14);
#pragma unroll
        for (int ks = 0; ks < 2; ++ks) {
            union { bf16x8 v; short s[8]; } pa;
#pragma unroll
            for (int j = 0; j < 4; ++j) {
                pa.s[j]     = f2bf(sfr[2 * ks][j]);
                pa.s[j + 4] = f2bf(sfr[2 * ks + 1][j]);
            }
            unsigned long long tr[8][2];
#pragma unroll
            for (int f8 = 0; f8 < 8; ++f8) {
                asm volatile("ds_read_b64_tr_b16 %0, %2 offset:%3\n\t"
                             "ds_read_b64_tr_b16 %1, %2 offset:%4"
                             : "=&v"(tr[f8][0]), "=&v"(tr[f8][1])
                             : "v"(vaddr),
                               "i"((f8 * 16 + 8 * ks) * 128),
                               "i"((f8 * 16 + 8 * ks + 4) * 128));
            }
            asm volatile("s_waitcnt lgkmcnt(0)" ::: "memory");
            __builtin_amdgcn_sched_barrier(0);
            __builtin_amdgcn_s_setprio(1);
#pragma unroll
            for (int f8 = 0; f8 < 8; ++f8) {
                union { bf16x8 v; unsigned long long q[2]; } vb;
                vb.q[0] = tr[f8][0];
                vb.q[1] = tr[f8][1];
                octx[f8] = MFMA32(pa.v, vb.v, octx[f8]);
            }
            __builtin_amdgcn_s_setprio(0);
        }
    }
#undef STAGE_K
#undef STAGE_V

    float linv[4];
#pragma unroll
    for (int i = 0; i < 4; ++i)
        linv[i] = 1.f / __shfl(lreg, hi * 4 + i);
#pragma unroll
    for (int i = 0; i < 4; ++i) {
        size_t rb = (size_t)(b * T_ + t0 + hi * 4 + i) * D_ + h * DH_;
#pragma unroll
        for (int f8 = 0; f8 < 8; ++f8)
            ctx[rb + f8 * 16 + lo] = __float2bfloat16(octx[f8][i] * linv[i]);
    }
}

// ---------------------------------------------------------------------------
extern "C" void kernel_launch(void* const* d_in, const int* in_sizes, int n_in,
                              void* d_out, int out_size, void* d_ws, size_t ws_size,
                              hipStream_t stream)
{
    (void)in_sizes; (void)n_in; (void)out_size; (void)ws_size;
    const float* x   = (const float*)d_in[0];
    const float* lns = (const float*)d_in[1];
    const float* lno = (const float*)d_in[2];
    const float* wq  = (const float*)d_in[3];
    const float* wk  = (const float*)d_in[4];
    const float* wv  = (const float*)d_in[5];
    const float* wo  = (const float*)d_in[6];
    const float* w1  = (const float*)d_in[7];
    const float* b1  = (const float*)d_in[8];
    const float* w2  = (const float*)d_in[9];
    const float* b2  = (const float*)d_in[10];
    float* out = (float*)d_out;

    char* ws = (char*)d_ws;
    __hip_bfloat16* wqkvT = (__hip_bfloat16*)(ws);                 // 6144x2048 bf16
    __hip_bfloat16* woT   = (__hip_bfloat16*)(ws + 25165824);      // 2048x2048
    __hip_bfloat16* w1T   = (__hip_bfloat16*)(ws + 33554432);      // 8192x2048
    __hip_bfloat16* w2T   = (__hip_bfloat16*)(ws + 67108864);      // 2048x8192
    __hip_bfloat16* xn    = (__hip_bfloat16*)(ws + 100663296);     // 4096x2048 (xn / xn2)
    __hip_bfloat16* qkv   = (__hip_bfloat16*)(ws + 117440512);     // 4096x6144
    __hip_bfloat16* hbuf  = qkv;                                   // 4096x8192 (aliases qkv+ctx)
    __hip_bfloat16* ctx   = (__hip_bfloat16*)(ws + 167772160);     // 4096x2048
    __hip_bfloat16* x1b   = (__hip_bfloat16*)(ws + 184549376);     // 4096x2048 bf16 (x1)

    transpose_cvt4<<<dim3(32, 64, 4), 256, 0, stream>>>(wq, wk, wv, wo, wqkvT, woT);
    transpose_cvt<<<dim3(128, 64), 256, 0, stream>>>(w1, w1T, 2048, 8192, 2048, 0);
    transpose_cvt<<<dim3(32, 256), 256, 0, stream>>>(w2, w2T, 8192, 2048, 8192, 0);

    ln_kernel<<<4096, 256, 0, stream>>>(x, lns, lno, xn);
    gemm8p<4, 128><<<dim3(24, 32), 512, 0, stream>>>(xn, wqkvT, qkv, nullptr, nullptr, 4096, 6144, 2048);
    attn_kernel<<<dim3(16, 32), 512, 0, stream>>>(qkv, ctx);
    gemmq<6><<<dim3(16, 32), 512, 0, stream>>>(ctx, woT, x1b, nullptr, x, 4096, 2048, 2048);
    ln_bf16_kernel<<<4096, 256, 0, stream>>>(x1b, lns, lno, xn);
    gemm8p<2, 256><<<dim3(32, 16), 512, 0, stream>>>(xn, w1T, hbuf, b1, nullptr, 4096, 8192, 2048);
    gemmq<5><<<dim3(16, 32), 512, 0, stream>>>(hbuf, w2T, out, b2, (const float*)x1b, 4096, 2048, 8192);
}